// Round 7
// baseline (318.265 us; speedup 1.0000x reference)
//
#include <hip/hip_runtime.h>
#include <hip/hip_bf16.h>
#include <math.h>

#define S_LEN 2048
#define BATCH 2
#define NH 16
#define DK 64
#define DM 1024
#define BS (BATCH * S_LEN)       /* 4096 rows */
#define BHS (BATCH * NH * S_LEN) /* 65536 head-rows */
#define TRP 72                   /* transpose-buffer pitch (shorts): 144B rows keep b128 aligned */
#define PSTR 72

/* fused prep-kernel block ranges */
#define NCONV (3 * BS * DM / 4 / 256) /* 12288 convert blocks */
#define NTRB (32 * 32 * 4)            /* 4096 big-transpose blocks */
#define NTRS 8                        /* small-transpose blocks */
#define NMSK (S_LEN * 64 / 256)       /* 512 maskpack blocks */

using bf16x8  = __attribute__((ext_vector_type(8))) __bf16;
using floatx4 = __attribute__((ext_vector_type(4))) float;
using ushort4v = __attribute__((ext_vector_type(4))) unsigned short;
using uint2v  = __attribute__((ext_vector_type(2))) unsigned int;

__device__ __forceinline__ unsigned short f2bf(float f) {
    union { float f; unsigned u; } v; v.f = f;
    unsigned r = v.u + 0x7fffu + ((v.u >> 16) & 1u);
    return (unsigned short)(r >> 16);
}

// packed RNE f32x2 -> bf16x2 (single VOP3)
__device__ __forceinline__ unsigned cvt_pk_bf16(float a, float b) {
    unsigned r;
    asm("v_cvt_pk_bf16_f32 %0, %1, %2" : "=v"(r) : "v"(a), "v"(b));
    return r;
}

// raw v_exp_f32 (2^x). Valid here: all inputs >= -23 (no denormal fixup needed),
// avoids the OCML range-check wrapper. Proven -11% on k_attn in round 6.
__device__ __forceinline__ float exp2_hw(float x) {
    float r;
    asm("v_exp_f32 %0, %1" : "=v"(r) : "v"(x));
    return r;
}
// raw v_rcp_f32 (~1 ulp), replaces the 9-inst IEEE divide sequence.
__device__ __forceinline__ float rcp_hw(float x) {
    float r;
    asm("v_rcp_f32 %0, %1" : "=v"(r) : "v"(x));
    return r;
}

__device__ __forceinline__ float fast_tanh(float x) {
    float e = exp2_hw(x * 2.8853900817779268f);
    return 1.0f - 2.0f * rcp_hw(e + 1.0f);   // e=inf -> rcp=0 -> 1; e=0 -> -1 (correct limits)
}

// async global->LDS, 16 bytes per lane. LDS dest must be wave-uniform base + lane*16.
__device__ __forceinline__ void gl2lds16(const void* g, void* l) {
    __builtin_amdgcn_global_load_lds(
        (__attribute__((address_space(1))) void*)(uintptr_t)g,
        (__attribute__((address_space(3))) void*)(uintptr_t)l,
        16, 0, 0);
}

// ---------------- fused prep: convert + transposes + maskpack in ONE launch ----------------
__global__ void k_prep(const float* __restrict__ q, const float* __restrict__ k,
                       const float* __restrict__ v,
                       unsigned short* __restrict__ qb, unsigned short* __restrict__ kb,
                       unsigned short* __restrict__ vb,
                       const float* __restrict__ wq, const float* __restrict__ wk,
                       const float* __restrict__ wv, const float* __restrict__ wo,
                       unsigned short* __restrict__ Wqt, unsigned short* __restrict__ Wkt,
                       unsigned short* __restrict__ Wvt, unsigned short* __restrict__ Wot,
                       const float* __restrict__ wnq, const float* __restrict__ wnk,
                       unsigned short* __restrict__ wnqt, unsigned short* __restrict__ wnkt,
                       const int* __restrict__ mask, unsigned int* __restrict__ mb) {
    __shared__ unsigned short tile[32][33];
    int bid = blockIdx.x;
    if (bid < NCONV) {
        // fp32 -> bf16 convert for Q,K,V
        const int N4 = BS * DM / 4;
        int i = bid * 256 + threadIdx.x;
        int which = i / N4;
        int off = i - which * N4;
        const floatx4* src = (const floatx4*)(which == 0 ? q : which == 1 ? k : v);
        unsigned short* dst = which == 0 ? qb : which == 1 ? kb : vb;
        floatx4 x = src[off];
        ushort4v o;
        unsigned p01 = cvt_pk_bf16(x[0], x[1]);
        unsigned p23 = cvt_pk_bf16(x[2], x[3]);
        o[0] = (unsigned short)p01; o[1] = (unsigned short)(p01 >> 16);
        o[2] = (unsigned short)p23; o[3] = (unsigned short)(p23 >> 16);
        ((ushort4v*)dst)[off] = o;
    } else if (bid < NCONV + NTRB) {
        // transpose 1024x1024 fp32 -> bf16 [N][K]
        int rel = bid - NCONV;
        int z = rel >> 10, xy = rel & 1023, by = xy >> 5, bx = xy & 31;
        const float* src = z == 0 ? wq : z == 1 ? wk : z == 2 ? wv : wo;
        unsigned short* dst = z == 0 ? Wqt : z == 1 ? Wkt : z == 2 ? Wvt : Wot;
        int tx = threadIdx.x & 31, ty = threadIdx.x >> 5;
#pragma unroll
        for (int i = 0; i < 4; i++) {
            int y = by * 32 + i * 8 + ty;
            tile[i * 8 + ty][tx] = f2bf(src[(size_t)y * DM + bx * 32 + tx]);
        }
        __syncthreads();
#pragma unroll
        for (int i = 0; i < 4; i++) {
            int r = bx * 32 + i * 8 + ty;
            dst[(size_t)r * DM + by * 32 + tx] = tile[tx][i * 8 + ty];
        }
    } else if (bid < NCONV + NTRB + NTRS) {
        // transpose 64x64 fp32 -> bf16 (wnq, wnk)
        int rel = bid - (NCONV + NTRB);
        int z = rel >> 2, by = (rel >> 1) & 1, bx = rel & 1;
        const float* src = z == 0 ? wnq : wnk;
        unsigned short* dst = z == 0 ? wnqt : wnkt;
        int tx = threadIdx.x & 31, ty = threadIdx.x >> 5;
#pragma unroll
        for (int i = 0; i < 4; i++) {
            int y = by * 32 + i * 8 + ty;
            tile[i * 8 + ty][tx] = f2bf(src[(size_t)y * DK + bx * 32 + tx]);
        }
        __syncthreads();
#pragma unroll
        for (int i = 0; i < 4; i++) {
            int r = bx * 32 + i * 8 + ty;
            dst[(size_t)r * DK + by * 32 + tx] = tile[tx][i * 8 + ty];
        }
    } else {
        // pack mask int32 -> bitmask
        int t = (bid - (NCONV + NTRB + NTRS)) * 256 + threadIdx.x;
        int row = t >> 6, w = t & 63;
        const int* p = mask + (size_t)row * S_LEN + w * 32;
        unsigned bits = 0;
#pragma unroll
        for (int i = 0; i < 32; i++) bits |= (p[i] != 0 ? 1u : 0u) << i;
        mb[t] = bits;
    }
}

// ---------------- merged QKV projection GEMM + fused feature map ----------------
// z==0: qfb row-major [bh][s][dk], = tanh(proj@wnq+bnq) * log2e/(8*temp[h])
// z==1: kfrag fragment order, = tanh(proj@wnk+bnk)
// z==2: vfrag in PV-fragment order
// grid x = m0 (fast axis): XCD = m0%8 for every n0 (gridDim.x=32, 32%8==0), so each
// A row-tile is fetched once and stays L2-resident across the n0 sweep.
// __launch_bounds__(256,4): cap VGPR at 128 so we hold 4 waves/SIMD -- acc(64)
// + frags(32) + epilogue temps is structurally near the 128 boundary and a
// spill-free >128 allocation would halve occupancy.
__global__ __launch_bounds__(256, 4) void k_gemm_qkv(
    const unsigned short* __restrict__ Qb, const unsigned short* __restrict__ Kb,
    const unsigned short* __restrict__ Vb,
    const unsigned short* __restrict__ Wqt, const unsigned short* __restrict__ Wkt,
    const unsigned short* __restrict__ Wvt,
    const float* __restrict__ bq, const float* __restrict__ bk, const float* __restrict__ bv,
    const unsigned short* __restrict__ wnqt, const unsigned short* __restrict__ wnkt,
    const float* __restrict__ bnq, const float* __restrict__ bnk,
    const float* __restrict__ temp,
    unsigned short* __restrict__ qfb, unsigned short* __restrict__ kfrag,
    unsigned short* __restrict__ vfrag) {
    const int K = DM;
    int z = blockIdx.z;
    const unsigned short* A  = z == 0 ? Qb  : z == 1 ? Kb  : Vb;
    const unsigned short* Wt = z == 0 ? Wqt : z == 1 ? Wkt : Wvt;
    const float* bias        = z == 0 ? bq  : z == 1 ? bk  : bv;
    int m0 = blockIdx.x * 128, n0 = blockIdx.y * 128;
    __shared__ unsigned short As[128 * 32];
    __shared__ unsigned short Bs[128 * 32];
    __shared__ unsigned short Tr[4][32 * TRP];
    int tid = threadIdx.x;
    int lane = tid & 63, wid = tid >> 6;
    int wy = wid >> 1, wx = wid & 1;
    int l16 = lane & 15, quad = lane >> 4;

    floatx4 acc[4][4] = {};

    for (int kt = 0; kt < K / 32; kt++) {
        int kk = kt * 32;
#pragma unroll
        for (int i = 0; i < 2; i++) {
            int c = i * 256 + tid;
            int row = c >> 2, seg = c & 3;
            gl2lds16(A + (size_t)(m0 + row) * K + kk + seg * 8, &As[c * 8]);
            gl2lds16(Wt + (size_t)(n0 + row) * K + kk + seg * 8, &Bs[c * 8]);
        }
        __syncthreads();
        bf16x8 af[4], bf[4];
#pragma unroll
        for (int mi = 0; mi < 4; mi++)
            af[mi] = *(const bf16x8*)&As[(wy * 64 + mi * 16 + l16) * 32 + quad * 8];
#pragma unroll
        for (int ni = 0; ni < 4; ni++)
            bf[ni] = *(const bf16x8*)&Bs[(wx * 64 + ni * 16 + l16) * 32 + quad * 8];
#pragma unroll
        for (int mi = 0; mi < 4; mi++)
#pragma unroll
            for (int ni = 0; ni < 4; ni++)
                acc[mi][ni] = __builtin_amdgcn_mfma_f32_16x16x32_bf16(af[mi], bf[ni], acc[mi][ni], 0, 0, 0);
        __syncthreads();
    }

    float bvv[4];
#pragma unroll
    for (int ni = 0; ni < 4; ni++) bvv[ni] = bias[n0 + wx * 64 + ni * 16 + l16];
    int head = (n0 + wx * 64) >> 6;
    int mbase = m0 + wy * 64;
    int b = mbase >> 11;
    int bh = b * NH + head;
    unsigned short* tw = &Tr[wid][0];

    if (z == 2) {
        int kt2 = (mbase & (S_LEN - 1)) >> 6;
        size_t tilebase = ((size_t)bh * 32 + kt2) * 4096;
#pragma unroll
        for (int hh = 0; hh < 2; hh++) {
#pragma unroll
            for (int ni2 = 0; ni2 < 2; ni2++) {
                int ni = hh * 2 + ni2;
#pragma unroll
                for (int mi = 0; mi < 4; mi++) {
                    unsigned p01 = cvt_pk_bf16(acc[mi][ni][0] + bvv[ni], acc[mi][ni][1] + bvv[ni]);
                    unsigned p23 = cvt_pk_bf16(acc[mi][ni][2] + bvv[ni], acc[mi][ni][3] + bvv[ni]);
                    int ad = (ni2 * 16 + l16) * TRP + mi * 16 + quad * 4;
                    *(unsigned*)&tw[ad] = p01;
                    *(unsigned*)&tw[ad + 2] = p23;
                }
            }
#pragma unroll
            for (int c = 0; c < 4; c++) {
                int ad = ((c >> 1) * 16 + l16) * TRP + (c & 1) * 32 + quad * 8;
                bf16x8 vv = *(const bf16x8*)&tw[ad];
                *(bf16x8*)&vfrag[tilebase + (size_t)(4 * hh + c) * 512 + lane * 8] = vv;
            }
        }
    } else {
        const unsigned short* wn = z == 0 ? wnqt : wnkt;
        const float* bn = z == 0 ? bnq : bnk;
        float sc = z == 0 ? 1.4426950408889634f / (8.0f * temp[head]) : 1.0f;
        bf16x8 wf[4][2];
        float bnv[4];
#pragma unroll
        for (int ni = 0; ni < 4; ni++) {
            bnv[ni] = bn[ni * 16 + l16];
#pragma unroll
            for (int ks = 0; ks < 2; ks++)
                wf[ni][ks] = *(const bf16x8*)(wn + (size_t)(ni * 16 + l16) * DK + ks * 32 + quad * 8);
        }
        size_t rowbase = (size_t)((size_t)bh * S_LEN + (mbase & (S_LEN - 1))) * DK;
        int kt2 = (mbase & (S_LEN - 1)) >> 6;
        size_t tb = ((size_t)bh * 32 + kt2) * 4096;
#pragma unroll
        for (int hh = 0; hh < 2; hh++) {
            // 1) projection rows (+bias) -> Tr [m][d]
#pragma unroll
            for (int mi2 = 0; mi2 < 2; mi2++) {
                int mi = hh * 2 + mi2;
#pragma unroll
                for (int ni = 0; ni < 4; ni++) {
                    unsigned p01 = cvt_pk_bf16(acc[mi][ni][0] + bvv[ni], acc[mi][ni][1] + bvv[ni]);
                    unsigned p23 = cvt_pk_bf16(acc[mi][ni][2] + bvv[ni], acc[mi][ni][3] + bvv[ni]);
                    int ad = (mi2 * 16 + quad * 4) * TRP + ni * 16 + l16;
                    tw[ad] = (unsigned short)p01;
                    tw[ad + TRP] = (unsigned short)(p01 >> 16);
                    tw[ad + 2 * TRP] = (unsigned short)p23;
                    tw[ad + 3 * TRP] = (unsigned short)(p23 >> 16);
                }
            }
            // 2) feature GEMM from Tr A-frags (own wave slice; DS ops wave-ordered)
            floatx4 facc[2][4] = {};
#pragma unroll
            for (int mg = 0; mg < 2; mg++) {
                bf16x8 af2[2];
#pragma unroll
                for (int ks = 0; ks < 2; ks++)
                    af2[ks] = *(const bf16x8*)&tw[(mg * 16 + l16) * TRP + ks * 32 + quad * 8];
#pragma unroll
                for (int ni = 0; ni < 4; ni++) {
                    facc[mg][ni] = __builtin_amdgcn_mfma_f32_16x16x32_bf16(af2[0], wf[ni][0], facc[mg][ni], 0, 0, 0);
                    facc[mg][ni] = __builtin_amdgcn_mfma_f32_16x16x32_bf16(af2[1], wf[ni][1], facc[mg][ni], 0, 0, 0);
                }
            }
            // 3) tanh(+bias)*sc -> Tr [m][d']
#pragma unroll
            for (int mg = 0; mg < 2; mg++) {
#pragma unroll
                for (int ni = 0; ni < 4; ni++) {
                    float t0 = fast_tanh(facc[mg][ni][0] + bnv[ni]) * sc;
                    float t1 = fast_tanh(facc[mg][ni][1] + bnv[ni]) * sc;
                    float t2 = fast_tanh(facc[mg][ni][2] + bnv[ni]) * sc;
                    float t3 = fast_tanh(facc[mg][ni][3] + bnv[ni]) * sc;
                    unsigned p01 = cvt_pk_bf16(t0, t1);
                    unsigned p23 = cvt_pk_bf16(t2, t3);
                    int ad = (mg * 16 + quad * 4) * TRP + ni * 16 + l16;
                    tw[ad] = (unsigned short)p01;
                    tw[ad + TRP] = (unsigned short)(p01 >> 16);
                    tw[ad + 2 * TRP] = (unsigned short)p23;
                    tw[ad + 3 * TRP] = (unsigned short)(p23 >> 16);
                }
            }
            // 4) store
            if (z == 0) {
#pragma unroll
                for (int c = 0; c < 4; c++) {
                    int g = c * 64 + lane;
                    int ml = g >> 3, dc = g & 7;
                    bf16x8 vv = *(const bf16x8*)&tw[ml * TRP + dc * 8];
                    *(bf16x8*)&qfb[rowbase + (size_t)(hh * 32 + ml) * DK + dc * 8] = vv;
                }
            } else {
#pragma unroll
                for (int c = 0; c < 4; c++) {
                    int ad = ((c >> 1) * 16 + l16) * TRP + (c & 1) * 32 + quad * 8;
                    bf16x8 vv = *(const bf16x8*)&tw[ad];
                    *(bf16x8*)&kfrag[tb + (size_t)(hh * 4 + c) * 512 + lane * 8] = vv;
                }
            }
        }
    }
}

// ---------------- out-projection GEMM: 128x64 tiles (2 blocks/CU), fp32 out ----------------
// grid x = m0 (fast axis): ctx row-tiles fetched once instead of once per XCD.
__global__ __launch_bounds__(256) void k_gemm_out(const unsigned short* __restrict__ A,
                                                  const unsigned short* __restrict__ Wt,
                                                  const float* __restrict__ bias,
                                                  float* __restrict__ out_f32) {
    const int K = DM;
    int m0 = blockIdx.x * 128, n0 = blockIdx.y * 64;
    __shared__ unsigned short As[128 * 32];
    __shared__ unsigned short Bs[64 * 32];
    int tid = threadIdx.x;
    int lane = tid & 63, wid = tid >> 6;
    int l16 = lane & 15, quad = lane >> 4;

    floatx4 acc[2][4] = {};

    for (int kt = 0; kt < K / 32; kt++) {
        int kk = kt * 32;
#pragma unroll
        for (int i = 0; i < 2; i++) {
            int c = i * 256 + tid;
            gl2lds16(A + (size_t)(m0 + (c >> 2)) * K + kk + (c & 3) * 8, &As[c * 8]);
        }
        gl2lds16(Wt + (size_t)(n0 + (tid >> 2)) * K + kk + (tid & 3) * 8, &Bs[tid * 8]);
        __syncthreads();
        bf16x8 af[2], bf[4];
#pragma unroll
        for (int mi = 0; mi < 2; mi++)
            af[mi] = *(const bf16x8*)&As[(wid * 32 + mi * 16 + l16) * 32 + quad * 8];
#pragma unroll
        for (int ni = 0; ni < 4; ni++)
            bf[ni] = *(const bf16x8*)&Bs[(ni * 16 + l16) * 32 + quad * 8];
#pragma unroll
        for (int mi = 0; mi < 2; mi++)
#pragma unroll
            for (int ni = 0; ni < 4; ni++)
                acc[mi][ni] = __builtin_amdgcn_mfma_f32_16x16x32_bf16(af[mi], bf[ni], acc[mi][ni], 0, 0, 0);
        __syncthreads();
    }

#pragma unroll
    for (int mi = 0; mi < 2; mi++) {
#pragma unroll
        for (int ni = 0; ni < 4; ni++) {
            int col = n0 + ni * 16 + l16;
            float bvv = bias[col];
#pragma unroll
            for (int r = 0; r < 4; r++) {
                int row = m0 + wid * 32 + mi * 16 + quad * 4 + r;
                out_f32[(size_t)row * DM + col] = acc[mi][ni][r] + bvv;
            }
        }
    }
}

// ---------------- flash attention, S^T formulation, 16 q-rows per wave ----------------
// Round-6 base (70 us, both pipes 61% -> latency-chain-bound). This round: split
// the P LDS round-trip so its ~120cy write->read wait is hidden instead of exposed:
//   8 QK MFMAs (grouped, pipelined) -> sm(kbk0/1) -> issue pa0 read
//   -> sm(kbk2/3) [hides pa0 wait] -> issue pa1 read -> PV(pa0) [hides pa1 wait]
//   -> PV(pa1).
// DS ops are wave-ordered, so pa0's read (issued after kbk0/1 writes) sees exactly
// the data it needs; the compiler's lgkmcnt waits land after the hiding work.
// Falsified by A/B: barrier-free K (r1), setprio (r2), 2-wave blocks/P-swizzle (r4).
// grid x = bh: dispatch%8 == bh%8 pins each head's K/V to one XCD L2.
__global__ __launch_bounds__(256, 4) void k_attn(const unsigned short* __restrict__ qf,
                                                 const unsigned short* __restrict__ kfr,
                                                 const unsigned short* __restrict__ vfr,
                                                 const unsigned long long* __restrict__ mb64,
                                                 unsigned short* __restrict__ ctx) {
    int tid = threadIdx.x, lane = tid & 63, wid = tid >> 6;
    int l16 = lane & 15, quad = lane >> 4;
    int bh = blockIdx.x;
    int b = bh >> 4, h = bh & 15;
    int q0 = blockIdx.y * 64 + wid * 16;

    const unsigned short* qfb = qf + (size_t)bh * S_LEN * DK;
    const unsigned short* kbase = kfr + (size_t)bh * 32 * 4096;
    const unsigned short* vbase = vfr + (size_t)bh * 32 * 4096;

    __shared__ unsigned short Kbuf[2][4096];
    __shared__ unsigned short Plds[4][16 * PSTR];
    unsigned short* myP = Plds[wid];

    union { bf16x8 v; unsigned short u[8]; } one_u;
#pragma unroll
    for (int j = 0; j < 8; j++) one_u.u[j] = 0x3F80;  // bf16 1.0
    bf16x8 ones = one_u.v;

    // Q as B-operand: lane l16 = q-row, k = d
    bf16x8 bq[2];
#pragma unroll
    for (int ks = 0; ks < 2; ks++)
        bq[ks] = *(const bf16x8*)(qfb + (size_t)(q0 + l16) * DK + ks * 32 + quad * 8);

    gl2lds16(kbase + tid * 8, &Kbuf[0][tid * 8]);
    gl2lds16(kbase + 2048 + tid * 8, &Kbuf[0][2048 + tid * 8]);

    floatx4 oacc[4] = {};
    floatx4 lacc = {};
    const unsigned long long* mq = mb64 + (size_t)(q0 + l16) * 32;

    for (int kt = 0; kt < 32; kt++) {
        __syncthreads();   // tile kt staged (issued a full iteration ago); prev reads done
        int nb = (kt + 1) & 1;
        const unsigned short* kn = kbase + (size_t)((kt + 1) & 31) * 4096;
        gl2lds16(kn + tid * 8, &Kbuf[nb][tid * 8]);
        gl2lds16(kn + 2048 + tid * 8, &Kbuf[nb][2048 + tid * 8]);
        // V prefetch (coalesced, consumed after softmax)
        const unsigned short* vt = vbase + (size_t)kt * 4096 + lane * 8;
        bf16x8 vf[8];
#pragma unroll
        for (int i = 0; i < 8; i++) vf[i] = *(const bf16x8*)(vt + i * 512);
        unsigned long long mw = mq[kt];
        const unsigned short* kb = &Kbuf[kt & 1][lane * 8];
        bf16x8 kf8[8];
#pragma unroll
        for (int i = 0; i < 8; i++) kf8[i] = *(const bf16x8*)(kb + i * 512);
        unsigned short* pw = myP + l16 * PSTR;
        // all 8 QK MFMAs back-to-back (independent, pipeline the MFMA unit)
        floatx4 sv[4];
#pragma unroll
        for (int kbk = 0; kbk < 4; kbk++) {
            floatx4 s = {};
            s = __builtin_amdgcn_mfma_f32_16x16x32_bf16(kf8[kbk * 2], bq[0], s, 0, 0, 0);
            s = __builtin_amdgcn_mfma_f32_16x16x32_bf16(kf8[kbk * 2 + 1], bq[1], s, 0, 0, 0);
            sv[kbk] = s;
        }
        // softmax kbk 0/1 -> P cols 0..31
#pragma unroll
        for (int kbk = 0; kbk < 2; kbk++) {
            unsigned w = (unsigned)(mw >> (kbk * 16 + quad * 4));
            float p0 = exp2_hw((w & 1u) ? sv[kbk][0] : -23.0f);
            float p1 = exp2_hw((w & 2u) ? sv[kbk][1] : -23.0f);
            float p2 = exp2_hw((w & 4u) ? sv[kbk][2] : -23.0f);
            float p3 = exp2_hw((w & 8u) ? sv[kbk][3] : -23.0f);
            uint2v pp;
            pp[0] = cvt_pk_bf16(p0, p1);
            pp[1] = cvt_pk_bf16(p2, p3);
            *(uint2v*)&pw[kbk * 16 + quad * 4] = pp;
        }
        // issue pa0 read now; its wait hides under kbk2/3 softmax below
        bf16x8 pa0 = *(const bf16x8*)&myP[l16 * PSTR + quad * 8];
        // softmax kbk 2/3 -> P cols 32..63
#pragma unroll
        for (int kbk = 2; kbk < 4; kbk++) {
            unsigned w = (unsigned)(mw >> (kbk * 16 + quad * 4));
            float p0 = exp2_hw((w & 1u) ? sv[kbk][0] : -23.0f);
            float p1 = exp2_hw((w & 2u) ? sv[kbk][1] : -23.0f);
            float p2 = exp2_hw((w & 4u) ? sv[kbk][2] : -23.0f);
            float p3 = exp2_hw((w & 8u) ? sv[kbk][3] : -23.0f);
            uint2v pp;
            pp[0] = cvt_pk_bf16(p0, p1);
            pp[1] = cvt_pk_bf16(p2, p3);
            *(uint2v*)&pw[kbk * 16 + quad * 4] = pp;
        }
        // issue pa1 read; its wait hides under pa0's 5 MFMAs
        bf16x8 pa1 = *(const bf16x8*)&myP[l16 * PSTR + 32 + quad * 8];
        // PV + row-sum for the k 0..31 half
        lacc = __builtin_amdgcn_mfma_f32_16x16x32_bf16(pa0, ones, lacc, 0, 0, 0);
#pragma unroll
        for (int ni = 0; ni < 4; ni++)
            oacc[ni] = __builtin_amdgcn_mfma_f32_16x16x32_bf16(pa0, vf[ni * 2], oacc[ni], 0, 0, 0);
        // PV + row-sum for the k 32..63 half
        lacc = __builtin_amdgcn_mfma_f32_16x16x32_bf16(pa1, ones, lacc, 0, 0, 0);
#pragma unroll
        for (int ni = 0; ni < 4; ni++)
            oacc[ni] = __builtin_amdgcn_mfma_f32_16x16x32_bf16(pa1, vf[ni * 2 + 1], oacc[ni], 0, 0, 0);
    }
    // epilogue: lacc rows align with oacc rows (q = quad*4+r) -> no cross-lane work
    float inv[4];
#pragma unroll
    for (int r = 0; r < 4; r++) inv[r] = rcp_hw(lacc[r]);
#pragma unroll
    for (int ni = 0; ni < 4; ni++) {
        int d = ni * 16 + l16;
#pragma unroll
        for (int r = 0; r < 4; r++) {
            int s = q0 + quad * 4 + r;
            ctx[(size_t)(b * S_LEN + s) * DM + h * DK + d] = f2bf(oacc[ni][r] * inv[r]);
        }
    }
}

// ---------------- RMSNorm ----------------
__global__ __launch_bounds__(256) void k_rmsnorm(const float* __restrict__ x,
                                                 const float* __restrict__ gamma,
                                                 float* __restrict__ out) {
    int row = blockIdx.x, tid = threadIdx.x;
    const floatx4* xr = (const floatx4*)(x + (size_t)row * DM);
    floatx4 v = xr[tid];
    float ss = v[0] * v[0] + v[1] * v[1] + v[2] * v[2] + v[3] * v[3];
#pragma unroll
    for (int off = 1; off < 64; off <<= 1) ss += __shfl_xor(ss, off);
    __shared__ float red[4];
    int lane = tid & 63, wid = tid >> 6;
    if (lane == 0) red[wid] = ss;
    __syncthreads();
    float tot = red[0] + red[1] + red[2] + red[3];
    float rms = rsqrtf(tot * (1.0f / DM) + 1e-6f);
    floatx4 g = ((const floatx4*)gamma)[tid];
    floatx4 o;
    o[0] = v[0] * rms * g[0];
    o[1] = v[1] * rms * g[1];
    o[2] = v[2] * rms * g[2];
    o[3] = v[3] * rms * g[3];
    ((floatx4*)(out + (size_t)row * DM))[tid] = o;
}

extern "C" void kernel_launch(void* const* d_in, const int* in_sizes, int n_in,
                              void* d_out, int out_size, void* d_ws, size_t ws_size,
                              hipStream_t stream) {
    const float* Q = (const float*)d_in[0];
    const float* K = (const float*)d_in[1];
    const float* V = (const float*)d_in[2];
    const int* mask = (const int*)d_in[3];
    const float* wq = (const float*)d_in[4];
    const float* bq = (const float*)d_in[5];
    const float* wk = (const float*)d_in[6];
    const float* bk = (const float*)d_in[7];
    const float* wv = (const float*)d_in[8];
    const float* bv = (const float*)d_in[9];
    const float* wo = (const float*)d_in[10];
    const float* bo = (const float*)d_in[11];
    const float* wnq = (const float*)d_in[12];
    const float* bnq = (const float*)d_in[13];
    const float* wnk = (const float*)d_in[14];
    const float* bnk = (const float*)d_in[15];
    const float* temp = (const float*)d_in[16];
    const float* gamma = (const float*)d_in[17];

    char* w = (char*)d_ws;
    size_t o = 0;
    auto alloc = [&](size_t bytes) {
        char* p = w + o;
        o += (bytes + 255) & ~(size_t)255;
        return p;
    };
    unsigned short* Qb = (unsigned short*)alloc((size_t)BS * DM * 2);
    unsigned short* Kb = (unsigned short*)alloc((size_t)BS * DM * 2);
    unsigned short* Vb = (unsigned short*)alloc((size_t)BS * DM * 2);
    unsigned short* Wqt = (unsigned short*)alloc((size_t)DM * DM * 2);
    unsigned short* Wkt = (unsigned short*)alloc((size_t)DM * DM * 2);
    unsigned short* Wvt = (unsigned short*)alloc((size_t)DM * DM * 2);
    unsigned short* Wot = (unsigned short*)alloc((size_t)DM * DM * 2);
    unsigned short* wnqt = (unsigned short*)alloc((size_t)DK * DK * 2);
    unsigned short* wnkt = (unsigned short*)alloc((size_t)DK * DK * 2);
    unsigned short* vfrag = (unsigned short*)alloc((size_t)BHS * DK * 2);
    unsigned short* qfb = (unsigned short*)alloc((size_t)BHS * DK * 2);
    unsigned short* kfrag = (unsigned short*)alloc((size_t)BHS * DK * 2);
    unsigned int* mb = (unsigned int*)alloc((size_t)S_LEN * (S_LEN / 32) * 4);
    unsigned short* ctx = (unsigned short*)alloc((size_t)BS * DM * 2);
    float* outt = (float*)alloc((size_t)BS * DM * 4);

    k_prep<<<dim3(NCONV + NTRB + NTRS + NMSK), 256, 0, stream>>>(
        Q, K, V, Qb, Kb, Vb, wq, wk, wv, wo, Wqt, Wkt, Wvt, Wot,
        wnq, wnk, wnqt, wnkt, mask, mb);

    k_gemm_qkv<<<dim3(32, 8, 3), 256, 0, stream>>>(Qb, Kb, Vb, Wqt, Wkt, Wvt,
                                                   bq, bk, bv, wnqt, wnkt, bnq, bnk, temp,
                                                   qfb, kfrag, vfrag);

    k_attn<<<dim3(BATCH * NH, S_LEN / 64), 256, 0, stream>>>(
        qfb, kfrag, vfrag, (const unsigned long long*)mb, ctx);

    k_gemm_out<<<dim3(32, 16), 256, 0, stream>>>(ctx, Wot, bo, outt);
    k_rmsnorm<<<dim3(BS), 256, 0, stream>>>(outt, gamma, (float*)d_out);
}

// Round 8
// 284.648 us; speedup vs baseline: 1.1181x; 1.1181x over previous
//
#include <hip/hip_runtime.h>
#include <hip/hip_bf16.h>
#include <math.h>

#define S_LEN 2048
#define BATCH 2
#define NH 16
#define DK 64
#define DM 1024
#define BS (BATCH * S_LEN)       /* 4096 rows */
#define BHS (BATCH * NH * S_LEN) /* 65536 head-rows */
#define TRP 72                   /* transpose-buffer pitch (shorts): 144B rows keep b128 aligned */
#define PSTR 72

/* fused prep-kernel block ranges */
#define NCONV (3 * BS * DM / 4 / 256) /* 12288 convert blocks */
#define NTRB (32 * 32 * 4)            /* 4096 big-transpose blocks */
#define NTRS 8                        /* small-transpose blocks */
#define NMSK (S_LEN * 64 / 256)       /* 512 maskpack blocks */

using bf16x8  = __attribute__((ext_vector_type(8))) __bf16;
using floatx4 = __attribute__((ext_vector_type(4))) float;
using ushort4v = __attribute__((ext_vector_type(4))) unsigned short;
using uint2v  = __attribute__((ext_vector_type(2))) unsigned int;

__device__ __forceinline__ unsigned short f2bf(float f) {
    union { float f; unsigned u; } v; v.f = f;
    unsigned r = v.u + 0x7fffu + ((v.u >> 16) & 1u);
    return (unsigned short)(r >> 16);
}

// packed RNE f32x2 -> bf16x2 (single VOP3)
__device__ __forceinline__ unsigned cvt_pk_bf16(float a, float b) {
    unsigned r;
    asm("v_cvt_pk_bf16_f32 %0, %1, %2" : "=v"(r) : "v"(a), "v"(b));
    return r;
}

// raw v_exp_f32 (2^x). Valid here: all inputs >= -23 (no denormal fixup needed),
// avoids the OCML range-check wrapper. Proven -11% on k_attn in round 6.
__device__ __forceinline__ float exp2_hw(float x) {
    float r;
    asm("v_exp_f32 %0, %1" : "=v"(r) : "v"(x));
    return r;
}
// raw v_rcp_f32 (~1 ulp), replaces the 9-inst IEEE divide sequence.
__device__ __forceinline__ float rcp_hw(float x) {
    float r;
    asm("v_rcp_f32 %0, %1" : "=v"(r) : "v"(x));
    return r;
}

__device__ __forceinline__ float fast_tanh(float x) {
    float e = exp2_hw(x * 2.8853900817779268f);
    return 1.0f - 2.0f * rcp_hw(e + 1.0f);   // e=inf -> rcp=0 -> 1; e=0 -> -1 (correct limits)
}

// async global->LDS, 16 bytes per lane. LDS dest must be wave-uniform base + lane*16.
__device__ __forceinline__ void gl2lds16(const void* g, void* l) {
    __builtin_amdgcn_global_load_lds(
        (__attribute__((address_space(1))) void*)(uintptr_t)g,
        (__attribute__((address_space(3))) void*)(uintptr_t)l,
        16, 0, 0);
}

// ---------------- fused prep: convert + transposes + maskpack in ONE launch ----------------
__global__ void k_prep(const float* __restrict__ q, const float* __restrict__ k,
                       const float* __restrict__ v,
                       unsigned short* __restrict__ qb, unsigned short* __restrict__ kb,
                       unsigned short* __restrict__ vb,
                       const float* __restrict__ wq, const float* __restrict__ wk,
                       const float* __restrict__ wv, const float* __restrict__ wo,
                       unsigned short* __restrict__ Wqt, unsigned short* __restrict__ Wkt,
                       unsigned short* __restrict__ Wvt, unsigned short* __restrict__ Wot,
                       const float* __restrict__ wnq, const float* __restrict__ wnk,
                       unsigned short* __restrict__ wnqt, unsigned short* __restrict__ wnkt,
                       const int* __restrict__ mask, unsigned int* __restrict__ mb) {
    __shared__ unsigned short tile[32][33];
    int bid = blockIdx.x;
    if (bid < NCONV) {
        // fp32 -> bf16 convert for Q,K,V
        const int N4 = BS * DM / 4;
        int i = bid * 256 + threadIdx.x;
        int which = i / N4;
        int off = i - which * N4;
        const floatx4* src = (const floatx4*)(which == 0 ? q : which == 1 ? k : v);
        unsigned short* dst = which == 0 ? qb : which == 1 ? kb : vb;
        floatx4 x = src[off];
        ushort4v o;
        unsigned p01 = cvt_pk_bf16(x[0], x[1]);
        unsigned p23 = cvt_pk_bf16(x[2], x[3]);
        o[0] = (unsigned short)p01; o[1] = (unsigned short)(p01 >> 16);
        o[2] = (unsigned short)p23; o[3] = (unsigned short)(p23 >> 16);
        ((ushort4v*)dst)[off] = o;
    } else if (bid < NCONV + NTRB) {
        // transpose 1024x1024 fp32 -> bf16 [N][K]
        int rel = bid - NCONV;
        int z = rel >> 10, xy = rel & 1023, by = xy >> 5, bx = xy & 31;
        const float* src = z == 0 ? wq : z == 1 ? wk : z == 2 ? wv : wo;
        unsigned short* dst = z == 0 ? Wqt : z == 1 ? Wkt : z == 2 ? Wvt : Wot;
        int tx = threadIdx.x & 31, ty = threadIdx.x >> 5;
#pragma unroll
        for (int i = 0; i < 4; i++) {
            int y = by * 32 + i * 8 + ty;
            tile[i * 8 + ty][tx] = f2bf(src[(size_t)y * DM + bx * 32 + tx]);
        }
        __syncthreads();
#pragma unroll
        for (int i = 0; i < 4; i++) {
            int r = bx * 32 + i * 8 + ty;
            dst[(size_t)r * DM + by * 32 + tx] = tile[tx][i * 8 + ty];
        }
    } else if (bid < NCONV + NTRB + NTRS) {
        // transpose 64x64 fp32 -> bf16 (wnq, wnk)
        int rel = bid - (NCONV + NTRB);
        int z = rel >> 2, by = (rel >> 1) & 1, bx = rel & 1;
        const float* src = z == 0 ? wnq : wnk;
        unsigned short* dst = z == 0 ? wnqt : wnkt;
        int tx = threadIdx.x & 31, ty = threadIdx.x >> 5;
#pragma unroll
        for (int i = 0; i < 4; i++) {
            int y = by * 32 + i * 8 + ty;
            tile[i * 8 + ty][tx] = f2bf(src[(size_t)y * DK + bx * 32 + tx]);
        }
        __syncthreads();
#pragma unroll
        for (int i = 0; i < 4; i++) {
            int r = bx * 32 + i * 8 + ty;
            dst[(size_t)r * DK + by * 32 + tx] = tile[tx][i * 8 + ty];
        }
    } else {
        // pack mask int32 -> bitmask
        int t = (bid - (NCONV + NTRB + NTRS)) * 256 + threadIdx.x;
        int row = t >> 6, w = t & 63;
        const int* p = mask + (size_t)row * S_LEN + w * 32;
        unsigned bits = 0;
#pragma unroll
        for (int i = 0; i < 32; i++) bits |= (p[i] != 0 ? 1u : 0u) << i;
        mb[t] = bits;
    }
}

// ---------------- merged QKV projection GEMM + fused feature map ----------------
// z==0: qfb row-major [bh][s][dk], = tanh(proj@wnq+bnq) * log2e/(8*temp[h])
// z==1: kfrag fragment order, = tanh(proj@wnk+bnk)
// z==2: vfrag in PV-fragment order
// grid x = m0 (fast axis): XCD = m0%8 for every n0 (gridDim.x=32, 32%8==0), so each
// A row-tile is fetched once and stays L2-resident across the n0 sweep.
// NO launch_bounds VGPR cap: round-7 A/B showed (256,4) costs +12us (epilogue spills).
__global__ __launch_bounds__(256) void k_gemm_qkv(
    const unsigned short* __restrict__ Qb, const unsigned short* __restrict__ Kb,
    const unsigned short* __restrict__ Vb,
    const unsigned short* __restrict__ Wqt, const unsigned short* __restrict__ Wkt,
    const unsigned short* __restrict__ Wvt,
    const float* __restrict__ bq, const float* __restrict__ bk, const float* __restrict__ bv,
    const unsigned short* __restrict__ wnqt, const unsigned short* __restrict__ wnkt,
    const float* __restrict__ bnq, const float* __restrict__ bnk,
    const float* __restrict__ temp,
    unsigned short* __restrict__ qfb, unsigned short* __restrict__ kfrag,
    unsigned short* __restrict__ vfrag) {
    const int K = DM;
    int z = blockIdx.z;
    const unsigned short* A  = z == 0 ? Qb  : z == 1 ? Kb  : Vb;
    const unsigned short* Wt = z == 0 ? Wqt : z == 1 ? Wkt : Wvt;
    const float* bias        = z == 0 ? bq  : z == 1 ? bk  : bv;
    int m0 = blockIdx.x * 128, n0 = blockIdx.y * 128;
    __shared__ unsigned short As[128 * 32];
    __shared__ unsigned short Bs[128 * 32];
    __shared__ unsigned short Tr[4][32 * TRP];
    int tid = threadIdx.x;
    int lane = tid & 63, wid = tid >> 6;
    int wy = wid >> 1, wx = wid & 1;
    int l16 = lane & 15, quad = lane >> 4;

    floatx4 acc[4][4] = {};

    for (int kt = 0; kt < K / 32; kt++) {
        int kk = kt * 32;
#pragma unroll
        for (int i = 0; i < 2; i++) {
            int c = i * 256 + tid;
            int row = c >> 2, seg = c & 3;
            gl2lds16(A + (size_t)(m0 + row) * K + kk + seg * 8, &As[c * 8]);
            gl2lds16(Wt + (size_t)(n0 + row) * K + kk + seg * 8, &Bs[c * 8]);
        }
        __syncthreads();
        bf16x8 af[4], bf[4];
#pragma unroll
        for (int mi = 0; mi < 4; mi++)
            af[mi] = *(const bf16x8*)&As[(wy * 64 + mi * 16 + l16) * 32 + quad * 8];
#pragma unroll
        for (int ni = 0; ni < 4; ni++)
            bf[ni] = *(const bf16x8*)&Bs[(wx * 64 + ni * 16 + l16) * 32 + quad * 8];
#pragma unroll
        for (int mi = 0; mi < 4; mi++)
#pragma unroll
            for (int ni = 0; ni < 4; ni++)
                acc[mi][ni] = __builtin_amdgcn_mfma_f32_16x16x32_bf16(af[mi], bf[ni], acc[mi][ni], 0, 0, 0);
        __syncthreads();
    }

    float bvv[4];
#pragma unroll
    for (int ni = 0; ni < 4; ni++) bvv[ni] = bias[n0 + wx * 64 + ni * 16 + l16];
    int head = (n0 + wx * 64) >> 6;
    int mbase = m0 + wy * 64;
    int b = mbase >> 11;
    int bh = b * NH + head;
    unsigned short* tw = &Tr[wid][0];

    if (z == 2) {
        int kt2 = (mbase & (S_LEN - 1)) >> 6;
        size_t tilebase = ((size_t)bh * 32 + kt2) * 4096;
#pragma unroll
        for (int hh = 0; hh < 2; hh++) {
#pragma unroll
            for (int ni2 = 0; ni2 < 2; ni2++) {
                int ni = hh * 2 + ni2;
#pragma unroll
                for (int mi = 0; mi < 4; mi++) {
                    unsigned p01 = cvt_pk_bf16(acc[mi][ni][0] + bvv[ni], acc[mi][ni][1] + bvv[ni]);
                    unsigned p23 = cvt_pk_bf16(acc[mi][ni][2] + bvv[ni], acc[mi][ni][3] + bvv[ni]);
                    int ad = (ni2 * 16 + l16) * TRP + mi * 16 + quad * 4;
                    *(unsigned*)&tw[ad] = p01;
                    *(unsigned*)&tw[ad + 2] = p23;
                }
            }
#pragma unroll
            for (int c = 0; c < 4; c++) {
                int ad = ((c >> 1) * 16 + l16) * TRP + (c & 1) * 32 + quad * 8;
                bf16x8 vv = *(const bf16x8*)&tw[ad];
                *(bf16x8*)&vfrag[tilebase + (size_t)(4 * hh + c) * 512 + lane * 8] = vv;
            }
        }
    } else {
        const unsigned short* wn = z == 0 ? wnqt : wnkt;
        const float* bn = z == 0 ? bnq : bnk;
        float sc = z == 0 ? 1.4426950408889634f / (8.0f * temp[head]) : 1.0f;
        bf16x8 wf[4][2];
        float bnv[4];
#pragma unroll
        for (int ni = 0; ni < 4; ni++) {
            bnv[ni] = bn[ni * 16 + l16];
#pragma unroll
            for (int ks = 0; ks < 2; ks++)
                wf[ni][ks] = *(const bf16x8*)(wn + (size_t)(ni * 16 + l16) * DK + ks * 32 + quad * 8);
        }
        size_t rowbase = (size_t)((size_t)bh * S_LEN + (mbase & (S_LEN - 1))) * DK;
        int kt2 = (mbase & (S_LEN - 1)) >> 6;
        size_t tb = ((size_t)bh * 32 + kt2) * 4096;
#pragma unroll
        for (int hh = 0; hh < 2; hh++) {
            // 1) projection rows (+bias) -> Tr [m][d]
#pragma unroll
            for (int mi2 = 0; mi2 < 2; mi2++) {
                int mi = hh * 2 + mi2;
#pragma unroll
                for (int ni = 0; ni < 4; ni++) {
                    unsigned p01 = cvt_pk_bf16(acc[mi][ni][0] + bvv[ni], acc[mi][ni][1] + bvv[ni]);
                    unsigned p23 = cvt_pk_bf16(acc[mi][ni][2] + bvv[ni], acc[mi][ni][3] + bvv[ni]);
                    int ad = (mi2 * 16 + quad * 4) * TRP + ni * 16 + l16;
                    tw[ad] = (unsigned short)p01;
                    tw[ad + TRP] = (unsigned short)(p01 >> 16);
                    tw[ad + 2 * TRP] = (unsigned short)p23;
                    tw[ad + 3 * TRP] = (unsigned short)(p23 >> 16);
                }
            }
            // 2) feature GEMM from Tr A-frags (own wave slice; DS ops wave-ordered)
            floatx4 facc[2][4] = {};
#pragma unroll
            for (int mg = 0; mg < 2; mg++) {
                bf16x8 af2[2];
#pragma unroll
                for (int ks = 0; ks < 2; ks++)
                    af2[ks] = *(const bf16x8*)&tw[(mg * 16 + l16) * TRP + ks * 32 + quad * 8];
#pragma unroll
                for (int ni = 0; ni < 4; ni++) {
                    facc[mg][ni] = __builtin_amdgcn_mfma_f32_16x16x32_bf16(af2[0], wf[ni][0], facc[mg][ni], 0, 0, 0);
                    facc[mg][ni] = __builtin_amdgcn_mfma_f32_16x16x32_bf16(af2[1], wf[ni][1], facc[mg][ni], 0, 0, 0);
                }
            }
            // 3) tanh(+bias)*sc -> Tr [m][d']
#pragma unroll
            for (int mg = 0; mg < 2; mg++) {
#pragma unroll
                for (int ni = 0; ni < 4; ni++) {
                    float t0 = fast_tanh(facc[mg][ni][0] + bnv[ni]) * sc;
                    float t1 = fast_tanh(facc[mg][ni][1] + bnv[ni]) * sc;
                    float t2 = fast_tanh(facc[mg][ni][2] + bnv[ni]) * sc;
                    float t3 = fast_tanh(facc[mg][ni][3] + bnv[ni]) * sc;
                    unsigned p01 = cvt_pk_bf16(t0, t1);
                    unsigned p23 = cvt_pk_bf16(t2, t3);
                    int ad = (mg * 16 + quad * 4) * TRP + ni * 16 + l16;
                    tw[ad] = (unsigned short)p01;
                    tw[ad + TRP] = (unsigned short)(p01 >> 16);
                    tw[ad + 2 * TRP] = (unsigned short)p23;
                    tw[ad + 3 * TRP] = (unsigned short)(p23 >> 16);
                }
            }
            // 4) store
            if (z == 0) {
#pragma unroll
                for (int c = 0; c < 4; c++) {
                    int g = c * 64 + lane;
                    int ml = g >> 3, dc = g & 7;
                    bf16x8 vv = *(const bf16x8*)&tw[ml * TRP + dc * 8];
                    *(bf16x8*)&qfb[rowbase + (size_t)(hh * 32 + ml) * DK + dc * 8] = vv;
                }
            } else {
#pragma unroll
                for (int c = 0; c < 4; c++) {
                    int ad = ((c >> 1) * 16 + l16) * TRP + (c & 1) * 32 + quad * 8;
                    bf16x8 vv = *(const bf16x8*)&tw[ad];
                    *(bf16x8*)&kfrag[tb + (size_t)(hh * 4 + c) * 512 + lane * 8] = vv;
                }
            }
        }
    }
}

// ---------------- out-projection GEMM: 128x64 tiles (2 blocks/CU), fp32 out ----------------
// grid x = m0 (fast axis): ctx row-tiles fetched once instead of once per XCD.
__global__ __launch_bounds__(256) void k_gemm_out(const unsigned short* __restrict__ A,
                                                  const unsigned short* __restrict__ Wt,
                                                  const float* __restrict__ bias,
                                                  float* __restrict__ out_f32) {
    const int K = DM;
    int m0 = blockIdx.x * 128, n0 = blockIdx.y * 64;
    __shared__ unsigned short As[128 * 32];
    __shared__ unsigned short Bs[64 * 32];
    int tid = threadIdx.x;
    int lane = tid & 63, wid = tid >> 6;
    int l16 = lane & 15, quad = lane >> 4;

    floatx4 acc[2][4] = {};

    for (int kt = 0; kt < K / 32; kt++) {
        int kk = kt * 32;
#pragma unroll
        for (int i = 0; i < 2; i++) {
            int c = i * 256 + tid;
            gl2lds16(A + (size_t)(m0 + (c >> 2)) * K + kk + (c & 3) * 8, &As[c * 8]);
        }
        gl2lds16(Wt + (size_t)(n0 + (tid >> 2)) * K + kk + (tid & 3) * 8, &Bs[tid * 8]);
        __syncthreads();
        bf16x8 af[2], bf[4];
#pragma unroll
        for (int mi = 0; mi < 2; mi++)
            af[mi] = *(const bf16x8*)&As[(wid * 32 + mi * 16 + l16) * 32 + quad * 8];
#pragma unroll
        for (int ni = 0; ni < 4; ni++)
            bf[ni] = *(const bf16x8*)&Bs[(ni * 16 + l16) * 32 + quad * 8];
#pragma unroll
        for (int mi = 0; mi < 2; mi++)
#pragma unroll
            for (int ni = 0; ni < 4; ni++)
                acc[mi][ni] = __builtin_amdgcn_mfma_f32_16x16x32_bf16(af[mi], bf[ni], acc[mi][ni], 0, 0, 0);
        __syncthreads();
    }

#pragma unroll
    for (int mi = 0; mi < 2; mi++) {
#pragma unroll
        for (int ni = 0; ni < 4; ni++) {
            int col = n0 + ni * 16 + l16;
            float bvv = bias[col];
#pragma unroll
            for (int r = 0; r < 4; r++) {
                int row = m0 + wid * 32 + mi * 16 + quad * 4 + r;
                out_f32[(size_t)row * DM + col] = acc[mi][ni][r] + bvv;
            }
        }
    }
}

// ---------------- flash attention, S^T formulation, 16 q-rows per wave ----------------
// Round-6 configuration verbatim -- best measured (70.0 us, total 282.0).
// Falsified by A/B: barrier-free K (r1, +15us), setprio (r2, null), 2-wave blocks /
// P-swizzle (r4, +3.5us), grouped-MFMA + early P-reads (r7, +23.7us -- hand
// scheduling defeats the compiler's fine-grained lgkmcnt interleave).
// Proven: raw v_exp/v_rcp diet (r6, -9us), bh-major grid / XCD pinning (r0, 5x FETCH).
__global__ __launch_bounds__(256, 4) void k_attn(const unsigned short* __restrict__ qf,
                                                 const unsigned short* __restrict__ kfr,
                                                 const unsigned short* __restrict__ vfr,
                                                 const unsigned long long* __restrict__ mb64,
                                                 unsigned short* __restrict__ ctx) {
    int tid = threadIdx.x, lane = tid & 63, wid = tid >> 6;
    int l16 = lane & 15, quad = lane >> 4;
    int bh = blockIdx.x;
    int b = bh >> 4, h = bh & 15;
    int q0 = blockIdx.y * 64 + wid * 16;

    const unsigned short* qfb = qf + (size_t)bh * S_LEN * DK;
    const unsigned short* kbase = kfr + (size_t)bh * 32 * 4096;
    const unsigned short* vbase = vfr + (size_t)bh * 32 * 4096;

    __shared__ unsigned short Kbuf[2][4096];
    __shared__ unsigned short Plds[4][16 * PSTR];
    unsigned short* myP = Plds[wid];

    union { bf16x8 v; unsigned short u[8]; } one_u;
#pragma unroll
    for (int j = 0; j < 8; j++) one_u.u[j] = 0x3F80;  // bf16 1.0
    bf16x8 ones = one_u.v;

    // Q as B-operand: lane l16 = q-row, k = d
    bf16x8 bq[2];
#pragma unroll
    for (int ks = 0; ks < 2; ks++)
        bq[ks] = *(const bf16x8*)(qfb + (size_t)(q0 + l16) * DK + ks * 32 + quad * 8);

    gl2lds16(kbase + tid * 8, &Kbuf[0][tid * 8]);
    gl2lds16(kbase + 2048 + tid * 8, &Kbuf[0][2048 + tid * 8]);

    floatx4 oacc[4] = {};
    floatx4 lacc = {};
    const unsigned long long* mq = mb64 + (size_t)(q0 + l16) * 32;

    for (int kt = 0; kt < 32; kt++) {
        __syncthreads();   // tile kt staged (issued a full iteration ago); prev reads done
        int nb = (kt + 1) & 1;
        const unsigned short* kn = kbase + (size_t)((kt + 1) & 31) * 4096;
        gl2lds16(kn + tid * 8, &Kbuf[nb][tid * 8]);
        gl2lds16(kn + 2048 + tid * 8, &Kbuf[nb][2048 + tid * 8]);
        // V prefetch (coalesced, consumed after softmax)
        const unsigned short* vt = vbase + (size_t)kt * 4096 + lane * 8;
        bf16x8 vf[8];
#pragma unroll
        for (int i = 0; i < 8; i++) vf[i] = *(const bf16x8*)(vt + i * 512);
        unsigned long long mw = mq[kt];
        const unsigned short* kb = &Kbuf[kt & 1][lane * 8];
        bf16x8 kf8[8];
#pragma unroll
        for (int i = 0; i < 8; i++) kf8[i] = *(const bf16x8*)(kb + i * 512);
        unsigned short* pw = myP + l16 * PSTR;
#pragma unroll
        for (int kbk = 0; kbk < 4; kbk++) {
            floatx4 s = {};
            s = __builtin_amdgcn_mfma_f32_16x16x32_bf16(kf8[kbk * 2], bq[0], s, 0, 0, 0);
            s = __builtin_amdgcn_mfma_f32_16x16x32_bf16(kf8[kbk * 2 + 1], bq[1], s, 0, 0, 0);
            unsigned w = (unsigned)(mw >> (kbk * 16 + quad * 4));
            float p0 = exp2_hw((w & 1u) ? s[0] : -23.0f);
            float p1 = exp2_hw((w & 2u) ? s[1] : -23.0f);
            float p2 = exp2_hw((w & 4u) ? s[2] : -23.0f);
            float p3 = exp2_hw((w & 8u) ? s[3] : -23.0f);
            uint2v pp;
            pp[0] = cvt_pk_bf16(p0, p1);
            pp[1] = cvt_pk_bf16(p2, p3);
            *(uint2v*)&pw[kbk * 16 + quad * 4] = pp;  // one b64 write
        }
        // P A-frags (own rows; DS ops wave-ordered)
        bf16x8 pa0 = *(const bf16x8*)&myP[l16 * PSTR + quad * 8];
        bf16x8 pa1 = *(const bf16x8*)&myP[l16 * PSTR + 32 + quad * 8];
        // row-sum on the MFMA pipe: l = P @ ones
        lacc = __builtin_amdgcn_mfma_f32_16x16x32_bf16(pa0, ones, lacc, 0, 0, 0);
        lacc = __builtin_amdgcn_mfma_f32_16x16x32_bf16(pa1, ones, lacc, 0, 0, 0);
#pragma unroll
        for (int ni = 0; ni < 4; ni++) {
            oacc[ni] = __builtin_amdgcn_mfma_f32_16x16x32_bf16(pa0, vf[ni * 2], oacc[ni], 0, 0, 0);
            oacc[ni] = __builtin_amdgcn_mfma_f32_16x16x32_bf16(pa1, vf[ni * 2 + 1], oacc[ni], 0, 0, 0);
        }
    }
    // epilogue: lacc rows align with oacc rows (q = quad*4+r) -> no cross-lane work
    float inv[4];
#pragma unroll
    for (int r = 0; r < 4; r++) inv[r] = rcp_hw(lacc[r]);
#pragma unroll
    for (int ni = 0; ni < 4; ni++) {
        int d = ni * 16 + l16;
#pragma unroll
        for (int r = 0; r < 4; r++) {
            int s = q0 + quad * 4 + r;
            ctx[(size_t)(b * S_LEN + s) * DM + h * DK + d] = f2bf(oacc[ni][r] * inv[r]);
        }
    }
}

// ---------------- RMSNorm ----------------
__global__ __launch_bounds__(256) void k_rmsnorm(const float* __restrict__ x,
                                                 const float* __restrict__ gamma,
                                                 float* __restrict__ out) {
    int row = blockIdx.x, tid = threadIdx.x;
    const floatx4* xr = (const floatx4*)(x + (size_t)row * DM);
    floatx4 v = xr[tid];
    float ss = v[0] * v[0] + v[1] * v[1] + v[2] * v[2] + v[3] * v[3];
#pragma unroll
    for (int off = 1; off < 64; off <<= 1) ss += __shfl_xor(ss, off);
    __shared__ float red[4];
    int lane = tid & 63, wid = tid >> 6;
    if (lane == 0) red[wid] = ss;
    __syncthreads();
    float tot = red[0] + red[1] + red[2] + red[3];
    float rms = rsqrtf(tot * (1.0f / DM) + 1e-6f);
    floatx4 g = ((const floatx4*)gamma)[tid];
    floatx4 o;
    o[0] = v[0] * rms * g[0];
    o[1] = v[1] * rms * g[1];
    o[2] = v[2] * rms * g[2];
    o[3] = v[3] * rms * g[3];
    ((floatx4*)(out + (size_t)row * DM))[tid] = o;
}

extern "C" void kernel_launch(void* const* d_in, const int* in_sizes, int n_in,
                              void* d_out, int out_size, void* d_ws, size_t ws_size,
                              hipStream_t stream) {
    const float* Q = (const float*)d_in[0];
    const float* K = (const float*)d_in[1];
    const float* V = (const float*)d_in[2];
    const int* mask = (const int*)d_in[3];
    const float* wq = (const float*)d_in[4];
    const float* bq = (const float*)d_in[5];
    const float* wk = (const float*)d_in[6];
    const float* bk = (const float*)d_in[7];
    const float* wv = (const float*)d_in[8];
    const float* bv = (const float*)d_in[9];
    const float* wo = (const float*)d_in[10];
    const float* bo = (const float*)d_in[11];
    const float* wnq = (const float*)d_in[12];
    const float* bnq = (const float*)d_in[13];
    const float* wnk = (const float*)d_in[14];
    const float* bnk = (const float*)d_in[15];
    const float* temp = (const float*)d_in[16];
    const float* gamma = (const float*)d_in[17];

    char* w = (char*)d_ws;
    size_t o = 0;
    auto alloc = [&](size_t bytes) {
        char* p = w + o;
        o += (bytes + 255) & ~(size_t)255;
        return p;
    };
    unsigned short* Qb = (unsigned short*)alloc((size_t)BS * DM * 2);
    unsigned short* Kb = (unsigned short*)alloc((size_t)BS * DM * 2);
    unsigned short* Vb = (unsigned short*)alloc((size_t)BS * DM * 2);
    unsigned short* Wqt = (unsigned short*)alloc((size_t)DM * DM * 2);
    unsigned short* Wkt = (unsigned short*)alloc((size_t)DM * DM * 2);
    unsigned short* Wvt = (unsigned short*)alloc((size_t)DM * DM * 2);
    unsigned short* Wot = (unsigned short*)alloc((size_t)DM * DM * 2);
    unsigned short* wnqt = (unsigned short*)alloc((size_t)DK * DK * 2);
    unsigned short* wnkt = (unsigned short*)alloc((size_t)DK * DK * 2);
    unsigned short* vfrag = (unsigned short*)alloc((size_t)BHS * DK * 2);
    unsigned short* qfb = (unsigned short*)alloc((size_t)BHS * DK * 2);
    unsigned short* kfrag = (unsigned short*)alloc((size_t)BHS * DK * 2);
    unsigned int* mb = (unsigned int*)alloc((size_t)S_LEN * (S_LEN / 32) * 4);
    unsigned short* ctx = (unsigned short*)alloc((size_t)BS * DM * 2);
    float* outt = (float*)alloc((size_t)BS * DM * 4);

    k_prep<<<dim3(NCONV + NTRB + NTRS + NMSK), 256, 0, stream>>>(
        Q, K, V, Qb, Kb, Vb, wq, wk, wv, wo, Wqt, Wkt, Wvt, Wot,
        wnq, wnk, wnqt, wnkt, mask, mb);

    k_gemm_qkv<<<dim3(32, 8, 3), 256, 0, stream>>>(Qb, Kb, Vb, Wqt, Wkt, Wvt,
                                                   bq, bk, bv, wnqt, wnkt, bnq, bnk, temp,
                                                   qfb, kfrag, vfrag);

    k_attn<<<dim3(BATCH * NH, S_LEN / 64), 256, 0, stream>>>(
        qfb, kfrag, vfrag, (const unsigned long long*)mb, ctx);

    k_gemm_out<<<dim3(32, 16), 256, 0, stream>>>(ctx, Wot, bo, outt);
    k_rmsnorm<<<dim3(BS), 256, 0, stream>>>(outt, gamma, (float*)d_out);
}

// Round 9
// 269.615 us; speedup vs baseline: 1.1804x; 1.0558x over previous
//
#include <hip/hip_runtime.h>
#include <hip/hip_bf16.h>
#include <math.h>

#define S_LEN 2048
#define BATCH 2
#define NH 16
#define DK 64
#define DM 1024
#define BS (BATCH * S_LEN)       /* 4096 rows */
#define BHS (BATCH * NH * S_LEN) /* 65536 head-rows */
#define TRP 72                   /* transpose-buffer pitch (shorts): 144B rows keep b128 aligned */
#define PSTR 72

/* fused prep-kernel block ranges */
#define NCONV (3 * BS * DM / 4 / 256) /* 12288 convert blocks */
#define NTRB2 (32 * 32 * 2)           /* 2048 transpose blocks (wv, wo) */
#define NCMP (32 * 32 * 2)            /* 2048 weight-composition blocks (Wq', Wk') */
#define NBC 8                         /* composed-bias blocks */
#define NMSK (S_LEN * 64 / 256)       /* 512 maskpack blocks */

using bf16x8  = __attribute__((ext_vector_type(8))) __bf16;
using floatx4 = __attribute__((ext_vector_type(4))) float;
using ushort4v = __attribute__((ext_vector_type(4))) unsigned short;
using uint2v  = __attribute__((ext_vector_type(2))) unsigned int;

__device__ __forceinline__ unsigned short f2bf(float f) {
    union { float f; unsigned u; } v; v.f = f;
    unsigned r = v.u + 0x7fffu + ((v.u >> 16) & 1u);
    return (unsigned short)(r >> 16);
}

// packed RNE f32x2 -> bf16x2 (single VOP3)
__device__ __forceinline__ unsigned cvt_pk_bf16(float a, float b) {
    unsigned r;
    asm("v_cvt_pk_bf16_f32 %0, %1, %2" : "=v"(r) : "v"(a), "v"(b));
    return r;
}

// raw v_exp_f32 (2^x). Inputs bounded (>= -23): no denormal fixup needed.
// Proven -11% on k_attn in round 6 vs OCML wrapper.
__device__ __forceinline__ float exp2_hw(float x) {
    float r;
    asm("v_exp_f32 %0, %1" : "=v"(r) : "v"(x));
    return r;
}
// raw v_rcp_f32 (~1 ulp), replaces the 9-inst IEEE divide sequence.
__device__ __forceinline__ float rcp_hw(float x) {
    float r;
    asm("v_rcp_f32 %0, %1" : "=v"(r) : "v"(x));
    return r;
}

__device__ __forceinline__ float fast_tanh(float x) {
    float e = exp2_hw(x * 2.8853900817779268f);
    return 1.0f - 2.0f * rcp_hw(e + 1.0f);   // e=inf -> 1; e=0 -> -1 (correct limits)
}

// async global->LDS, 16 bytes per lane. LDS dest must be wave-uniform base + lane*16.
__device__ __forceinline__ void gl2lds16(const void* g, void* l) {
    __builtin_amdgcn_global_load_lds(
        (__attribute__((address_space(1))) void*)(uintptr_t)g,
        (__attribute__((address_space(3))) void*)(uintptr_t)l,
        16, 0, 0);
}

// ---------------- fused prep: convert + transposes + weight composition + maskpack ----------------
// NEW (r9): the per-head feature transform composes into the projection weight:
//   tanh((X@Wq + bq)@wnq + bnq) = tanh(X@(Wq_h@wnq) + (bq_h@wnq + bnq))
// so we precompute Wq' / Wk' (block-diagonal composition, fp32 math -> bf16 once)
// and composed biases. This deletes the entire feature-GEMM epilogue in k_gemm_qkv.
__global__ void k_prep(const float* __restrict__ q, const float* __restrict__ k,
                       const float* __restrict__ v,
                       unsigned short* __restrict__ qb, unsigned short* __restrict__ kb,
                       unsigned short* __restrict__ vb,
                       const float* __restrict__ wq, const float* __restrict__ wk,
                       const float* __restrict__ wv, const float* __restrict__ wo,
                       unsigned short* __restrict__ Wqt, unsigned short* __restrict__ Wkt,
                       unsigned short* __restrict__ Wvt, unsigned short* __restrict__ Wot,
                       const float* __restrict__ wnq, const float* __restrict__ wnk,
                       const float* __restrict__ bq, const float* __restrict__ bk,
                       const float* __restrict__ bnq, const float* __restrict__ bnk,
                       float* __restrict__ bqc, float* __restrict__ bkc,
                       const int* __restrict__ mask, unsigned int* __restrict__ mb) {
    __shared__ unsigned short tile[32][33];
    __shared__ float Ab[32][65];   /* composition A tile, +1 col pad: conflict-free across i */
    __shared__ float Bb[64][32];   /* composition B tile (broadcast reads, no pad needed) */
    int bid = blockIdx.x;
    if (bid < NCONV) {
        // fp32 -> bf16 convert for Q,K,V
        const int N4 = BS * DM / 4;
        int i = bid * 256 + threadIdx.x;
        int which = i / N4;
        int off = i - which * N4;
        const floatx4* src = (const floatx4*)(which == 0 ? q : which == 1 ? k : v);
        unsigned short* dst = which == 0 ? qb : which == 1 ? kb : vb;
        floatx4 x = src[off];
        ushort4v o;
        unsigned p01 = cvt_pk_bf16(x[0], x[1]);
        unsigned p23 = cvt_pk_bf16(x[2], x[3]);
        o[0] = (unsigned short)p01; o[1] = (unsigned short)(p01 >> 16);
        o[2] = (unsigned short)p23; o[3] = (unsigned short)(p23 >> 16);
        ((ushort4v*)dst)[off] = o;
    } else if (bid < NCONV + NTRB2) {
        // transpose 1024x1024 fp32 -> bf16 [N][K] (wv, wo only; wq/wk go through composition)
        int rel = bid - NCONV;
        int z = rel >> 10, xy = rel & 1023, by = xy >> 5, bx = xy & 31;
        const float* src = z == 0 ? wv : wo;
        unsigned short* dst = z == 0 ? Wvt : Wot;
        int tx = threadIdx.x & 31, ty = threadIdx.x >> 5;
#pragma unroll
        for (int i = 0; i < 4; i++) {
            int y = by * 32 + i * 8 + ty;
            tile[i * 8 + ty][tx] = f2bf(src[(size_t)y * DM + bx * 32 + tx]);
        }
        __syncthreads();
#pragma unroll
        for (int i = 0; i < 4; i++) {
            int r = bx * 32 + i * 8 + ty;
            dst[(size_t)r * DM + by * 32 + tx] = tile[tx][i * 8 + ty];
        }
    } else if (bid < NCONV + NTRB2 + NCMP) {
        // composed weight: Wdst^T[o][i] = sum_d Wsrc[i][64h+d] * wn[d][j],  o=64h+j
        int rel = bid - (NCONV + NTRB2);
        int zz = rel >> 10;
        const float* wsrc = zz == 0 ? wq : wk;
        const float* wn = zz == 0 ? wnq : wnk;
        unsigned short* dst = zz == 0 ? Wqt : Wkt;
        int xy = rel & 1023, bo = xy >> 5, bi = xy & 31;
        int o0 = bo * 32, i0 = bi * 32;
        int h = o0 >> 6, j0 = o0 & 63;   /* 32-tile stays within one head (32 | 64) */
        int t = threadIdx.x;
        {
            int r = t >> 3, d8 = (t & 7) * 8;
            const float* s = wsrc + (size_t)(i0 + r) * DM + h * 64 + d8;
#pragma unroll
            for (int u = 0; u < 8; u++) Ab[r][d8 + u] = s[u];
            int d = t >> 2, c8 = (t & 3) * 8;
            const float* s2 = wn + d * 64 + j0 + c8;
#pragma unroll
            for (int u = 0; u < 8; u++) Bb[d][c8 + u] = s2[u];
        }
        __syncthreads();
        int il = t & 31, ob = (t >> 5) * 4;
        float s0 = 0.f, s1 = 0.f, s2 = 0.f, s3 = 0.f;
#pragma unroll 8
        for (int d = 0; d < 64; d++) {
            float a = Ab[il][d];
            s0 += a * Bb[d][ob];
            s1 += a * Bb[d][ob + 1];
            s2 += a * Bb[d][ob + 2];
            s3 += a * Bb[d][ob + 3];
        }
        dst[(size_t)(o0 + ob) * DM + i0 + il] = f2bf(s0);
        dst[(size_t)(o0 + ob + 1) * DM + i0 + il] = f2bf(s1);
        dst[(size_t)(o0 + ob + 2) * DM + i0 + il] = f2bf(s2);
        dst[(size_t)(o0 + ob + 3) * DM + i0 + il] = f2bf(s3);
    } else if (bid < NCONV + NTRB2 + NCMP + NBC) {
        // composed bias: b'[64h+j] = sum_d b[64h+d]*wn[d][j] + bn[j]  (fp32)
        int tg = (bid - (NCONV + NTRB2 + NCMP)) * 256 + threadIdx.x;  /* 0..2047 */
        int zz = tg >> 10;
        int o = tg & 1023;
        const float* bsrc = zz == 0 ? bq : bk;
        const float* bns = zz == 0 ? bnq : bnk;
        const float* wn = zz == 0 ? wnq : wnk;
        float* dst = zz == 0 ? bqc : bkc;
        int h = o >> 6, j = o & 63;
        float s = bns[j];
        for (int d = 0; d < 64; d++) s += bsrc[h * 64 + d] * wn[d * 64 + j];
        dst[o] = s;
    } else {
        // pack mask int32 -> bitmask
        int t = (bid - (NCONV + NTRB2 + NCMP + NBC)) * 256 + threadIdx.x;
        int row = t >> 6, w = t & 63;
        const int* p = mask + (size_t)row * S_LEN + w * 32;
        unsigned bits = 0;
#pragma unroll
        for (int i = 0; i < 32; i++) bits |= (p[i] != 0 ? 1u : 0u) << i;
        mb[t] = bits;
    }
}

// ---------------- merged QKV projection GEMM (composed weights) ----------------
// z==0: qfb row-major [bh][s][dk] = tanh(X@Wq' + bq') * log2e/(8*temp[h])
// z==1: kfrag fragment order     = tanh(X@Wk' + bk')
// z==2: vfrag in PV-fragment order = X@Wv + bv
// The feature-map GEMM is gone (composed into the weights in k_prep) -- the
// z=0/1 epilogue is now: tanh on acc -> one LDS layout pass -> store.
// grid x = m0 (fast axis): XCD = m0%8 for every n0, A row-tile L2-resident.
// NO launch_bounds VGPR cap (r7: the (256,4) cap cost +12us in spills).
__global__ __launch_bounds__(256) void k_gemm_qkv(
    const unsigned short* __restrict__ Qb, const unsigned short* __restrict__ Kb,
    const unsigned short* __restrict__ Vb,
    const unsigned short* __restrict__ Wqt, const unsigned short* __restrict__ Wkt,
    const unsigned short* __restrict__ Wvt,
    const float* __restrict__ bqc, const float* __restrict__ bkc,
    const float* __restrict__ bv,
    const float* __restrict__ temp,
    unsigned short* __restrict__ qfb, unsigned short* __restrict__ kfrag,
    unsigned short* __restrict__ vfrag) {
    const int K = DM;
    int z = blockIdx.z;
    const unsigned short* A  = z == 0 ? Qb  : z == 1 ? Kb  : Vb;
    const unsigned short* Wt = z == 0 ? Wqt : z == 1 ? Wkt : Wvt;
    const float* bias        = z == 0 ? bqc : z == 1 ? bkc : bv;
    int m0 = blockIdx.x * 128, n0 = blockIdx.y * 128;
    __shared__ unsigned short As[128 * 32];
    __shared__ unsigned short Bs[128 * 32];
    __shared__ unsigned short Tr[4][32 * TRP];
    int tid = threadIdx.x;
    int lane = tid & 63, wid = tid >> 6;
    int wy = wid >> 1, wx = wid & 1;
    int l16 = lane & 15, quad = lane >> 4;

    floatx4 acc[4][4] = {};

    for (int kt = 0; kt < K / 32; kt++) {
        int kk = kt * 32;
#pragma unroll
        for (int i = 0; i < 2; i++) {
            int c = i * 256 + tid;
            int row = c >> 2, seg = c & 3;
            gl2lds16(A + (size_t)(m0 + row) * K + kk + seg * 8, &As[c * 8]);
            gl2lds16(Wt + (size_t)(n0 + row) * K + kk + seg * 8, &Bs[c * 8]);
        }
        __syncthreads();
        bf16x8 af[4], bf[4];
#pragma unroll
        for (int mi = 0; mi < 4; mi++)
            af[mi] = *(const bf16x8*)&As[(wy * 64 + mi * 16 + l16) * 32 + quad * 8];
#pragma unroll
        for (int ni = 0; ni < 4; ni++)
            bf[ni] = *(const bf16x8*)&Bs[(wx * 64 + ni * 16 + l16) * 32 + quad * 8];
#pragma unroll
        for (int mi = 0; mi < 4; mi++)
#pragma unroll
            for (int ni = 0; ni < 4; ni++)
                acc[mi][ni] = __builtin_amdgcn_mfma_f32_16x16x32_bf16(af[mi], bf[ni], acc[mi][ni], 0, 0, 0);
        __syncthreads();
    }

    float bvv[4];
#pragma unroll
    for (int ni = 0; ni < 4; ni++) bvv[ni] = bias[n0 + wx * 64 + ni * 16 + l16];
    int head = (n0 + wx * 64) >> 6;
    int mbase = m0 + wy * 64;
    int b = mbase >> 11;
    int bh = b * NH + head;
    unsigned short* tw = &Tr[wid][0];

    if (z == 2) {
        int kt2 = (mbase & (S_LEN - 1)) >> 6;
        size_t tilebase = ((size_t)bh * 32 + kt2) * 4096;
#pragma unroll
        for (int hh = 0; hh < 2; hh++) {
#pragma unroll
            for (int ni2 = 0; ni2 < 2; ni2++) {
                int ni = hh * 2 + ni2;
#pragma unroll
                for (int mi = 0; mi < 4; mi++) {
                    unsigned p01 = cvt_pk_bf16(acc[mi][ni][0] + bvv[ni], acc[mi][ni][1] + bvv[ni]);
                    unsigned p23 = cvt_pk_bf16(acc[mi][ni][2] + bvv[ni], acc[mi][ni][3] + bvv[ni]);
                    int ad = (ni2 * 16 + l16) * TRP + mi * 16 + quad * 4;
                    *(unsigned*)&tw[ad] = p01;
                    *(unsigned*)&tw[ad + 2] = p23;
                }
            }
#pragma unroll
            for (int c = 0; c < 4; c++) {
                int ad = ((c >> 1) * 16 + l16) * TRP + (c & 1) * 32 + quad * 8;
                bf16x8 vv = *(const bf16x8*)&tw[ad];
                *(bf16x8*)&vfrag[tilebase + (size_t)(4 * hh + c) * 512 + lane * 8] = vv;
            }
        }
    } else {
        float sc = z == 0 ? 1.4426950408889634f / (8.0f * temp[head]) : 1.0f;
        size_t rowbase = (size_t)((size_t)bh * S_LEN + (mbase & (S_LEN - 1))) * DK;
        int kt2 = (mbase & (S_LEN - 1)) >> 6;
        size_t tb = ((size_t)bh * 32 + kt2) * 4096;
#pragma unroll
        for (int hh = 0; hh < 2; hh++) {
            // tanh(+composed bias)*sc directly on acc -> Tr [m][d] layout
#pragma unroll
            for (int mi2 = 0; mi2 < 2; mi2++) {
                int mi = hh * 2 + mi2;
#pragma unroll
                for (int ni = 0; ni < 4; ni++) {
                    float t0 = fast_tanh(acc[mi][ni][0] + bvv[ni]) * sc;
                    float t1 = fast_tanh(acc[mi][ni][1] + bvv[ni]) * sc;
                    float t2 = fast_tanh(acc[mi][ni][2] + bvv[ni]) * sc;
                    float t3 = fast_tanh(acc[mi][ni][3] + bvv[ni]) * sc;
                    unsigned p01 = cvt_pk_bf16(t0, t1);
                    unsigned p23 = cvt_pk_bf16(t2, t3);
                    int ad = (mi2 * 16 + quad * 4) * TRP + ni * 16 + l16;
                    tw[ad] = (unsigned short)p01;
                    tw[ad + TRP] = (unsigned short)(p01 >> 16);
                    tw[ad + 2 * TRP] = (unsigned short)p23;
                    tw[ad + 3 * TRP] = (unsigned short)(p23 >> 16);
                }
            }
            // store (wave-private Tr; DS ops wave-ordered)
            if (z == 0) {
#pragma unroll
                for (int c = 0; c < 4; c++) {
                    int g = c * 64 + lane;
                    int ml = g >> 3, dc = g & 7;
                    bf16x8 vv = *(const bf16x8*)&tw[ml * TRP + dc * 8];
                    *(bf16x8*)&qfb[rowbase + (size_t)(hh * 32 + ml) * DK + dc * 8] = vv;
                }
            } else {
#pragma unroll
                for (int c = 0; c < 4; c++) {
                    int ad = ((c >> 1) * 16 + l16) * TRP + (c & 1) * 32 + quad * 8;
                    bf16x8 vv = *(const bf16x8*)&tw[ad];
                    *(bf16x8*)&kfrag[tb + (size_t)(hh * 4 + c) * 512 + lane * 8] = vv;
                }
            }
        }
    }
}

// ---------------- out-projection GEMM: 128x64 tiles (2 blocks/CU), fp32 out ----------------
// grid x = m0 (fast axis): ctx row-tiles fetched once instead of once per XCD.
__global__ __launch_bounds__(256) void k_gemm_out(const unsigned short* __restrict__ A,
                                                  const unsigned short* __restrict__ Wt,
                                                  const float* __restrict__ bias,
                                                  float* __restrict__ out_f32) {
    const int K = DM;
    int m0 = blockIdx.x * 128, n0 = blockIdx.y * 64;
    __shared__ unsigned short As[128 * 32];
    __shared__ unsigned short Bs[64 * 32];
    int tid = threadIdx.x;
    int lane = tid & 63, wid = tid >> 6;
    int l16 = lane & 15, quad = lane >> 4;

    floatx4 acc[2][4] = {};

    for (int kt = 0; kt < K / 32; kt++) {
        int kk = kt * 32;
#pragma unroll
        for (int i = 0; i < 2; i++) {
            int c = i * 256 + tid;
            gl2lds16(A + (size_t)(m0 + (c >> 2)) * K + kk + (c & 3) * 8, &As[c * 8]);
        }
        gl2lds16(Wt + (size_t)(n0 + (tid >> 2)) * K + kk + (tid & 3) * 8, &Bs[tid * 8]);
        __syncthreads();
        bf16x8 af[2], bf[4];
#pragma unroll
        for (int mi = 0; mi < 2; mi++)
            af[mi] = *(const bf16x8*)&As[(wid * 32 + mi * 16 + l16) * 32 + quad * 8];
#pragma unroll
        for (int ni = 0; ni < 4; ni++)
            bf[ni] = *(const bf16x8*)&Bs[(ni * 16 + l16) * 32 + quad * 8];
#pragma unroll
        for (int mi = 0; mi < 2; mi++)
#pragma unroll
            for (int ni = 0; ni < 4; ni++)
                acc[mi][ni] = __builtin_amdgcn_mfma_f32_16x16x32_bf16(af[mi], bf[ni], acc[mi][ni], 0, 0, 0);
        __syncthreads();
    }

#pragma unroll
    for (int mi = 0; mi < 2; mi++) {
#pragma unroll
        for (int ni = 0; ni < 4; ni++) {
            int col = n0 + ni * 16 + l16;
            float bvv = bias[col];
#pragma unroll
            for (int r = 0; r < 4; r++) {
                int row = m0 + wid * 32 + mi * 16 + quad * 4 + r;
                out_f32[(size_t)row * DM + col] = acc[mi][ni][r] + bvv;
            }
        }
    }
}

// ---------------- flash attention, S^T formulation, 16 q-rows per wave ----------------
// Round-6 configuration verbatim -- best measured (70.0 us, reproduced r8).
// Falsified by A/B: barrier-free K (r1, +15us), setprio (r2, null), 2-wave blocks /
// P-swizzle (r4, +3.5us), grouped-MFMA + early P-reads (r7, +23.7us).
// Proven: raw v_exp/v_rcp diet (r6, -9us), bh-major grid / XCD pinning (r0, 5x FETCH).
__global__ __launch_bounds__(256, 4) void k_attn(const unsigned short* __restrict__ qf,
                                                 const unsigned short* __restrict__ kfr,
                                                 const unsigned short* __restrict__ vfr,
                                                 const unsigned long long* __restrict__ mb64,
                                                 unsigned short* __restrict__ ctx) {
    int tid = threadIdx.x, lane = tid & 63, wid = tid >> 6;
    int l16 = lane & 15, quad = lane >> 4;
    int bh = blockIdx.x;
    int b = bh >> 4, h = bh & 15;
    int q0 = blockIdx.y * 64 + wid * 16;

    const unsigned short* qfb = qf + (size_t)bh * S_LEN * DK;
    const unsigned short* kbase = kfr + (size_t)bh * 32 * 4096;
    const unsigned short* vbase = vfr + (size_t)bh * 32 * 4096;

    __shared__ unsigned short Kbuf[2][4096];
    __shared__ unsigned short Plds[4][16 * PSTR];
    unsigned short* myP = Plds[wid];

    union { bf16x8 v; unsigned short u[8]; } one_u;
#pragma unroll
    for (int j = 0; j < 8; j++) one_u.u[j] = 0x3F80;  // bf16 1.0
    bf16x8 ones = one_u.v;

    // Q as B-operand: lane l16 = q-row, k = d
    bf16x8 bq[2];
#pragma unroll
    for (int ks = 0; ks < 2; ks++)
        bq[ks] = *(const bf16x8*)(qfb + (size_t)(q0 + l16) * DK + ks * 32 + quad * 8);

    gl2lds16(kbase + tid * 8, &Kbuf[0][tid * 8]);
    gl2lds16(kbase + 2048 + tid * 8, &Kbuf[0][2048 + tid * 8]);

    floatx4 oacc[4] = {};
    floatx4 lacc = {};
    const unsigned long long* mq = mb64 + (size_t)(q0 + l16) * 32;

    for (int kt = 0; kt < 32; kt++) {
        __syncthreads();   // tile kt staged (issued a full iteration ago); prev reads done
        int nb = (kt + 1) & 1;
        const unsigned short* kn = kbase + (size_t)((kt + 1) & 31) * 4096;
        gl2lds16(kn + tid * 8, &Kbuf[nb][tid * 8]);
        gl2lds16(kn + 2048 + tid * 8, &Kbuf[nb][2048 + tid * 8]);
        // V prefetch (coalesced, consumed after softmax)
        const unsigned short* vt = vbase + (size_t)kt * 4096 + lane * 8;
        bf16x8 vf[8];
#pragma unroll
        for (int i = 0; i < 8; i++) vf[i] = *(const bf16x8*)(vt + i * 512);
        unsigned long long mw = mq[kt];
        const unsigned short* kb = &Kbuf[kt & 1][lane * 8];
        bf16x8 kf8[8];
#pragma unroll
        for (int i = 0; i < 8; i++) kf8[i] = *(const bf16x8*)(kb + i * 512);
        unsigned short* pw = myP + l16 * PSTR;
#pragma unroll
        for (int kbk = 0; kbk < 4; kbk++) {
            floatx4 s = {};
            s = __builtin_amdgcn_mfma_f32_16x16x32_bf16(kf8[kbk * 2], bq[0], s, 0, 0, 0);
            s = __builtin_amdgcn_mfma_f32_16x16x32_bf16(kf8[kbk * 2 + 1], bq[1], s, 0, 0, 0);
            unsigned w = (unsigned)(mw >> (kbk * 16 + quad * 4));
            float p0 = exp2_hw((w & 1u) ? s[0] : -23.0f);
            float p1 = exp2_hw((w & 2u) ? s[1] : -23.0f);
            float p2 = exp2_hw((w & 4u) ? s[2] : -23.0f);
            float p3 = exp2_hw((w & 8u) ? s[3] : -23.0f);
            uint2v pp;
            pp[0] = cvt_pk_bf16(p0, p1);
            pp[1] = cvt_pk_bf16(p2, p3);
            *(uint2v*)&pw[kbk * 16 + quad * 4] = pp;  // one b64 write
        }
        // P A-frags (own rows; DS ops wave-ordered)
        bf16x8 pa0 = *(const bf16x8*)&myP[l16 * PSTR + quad * 8];
        bf16x8 pa1 = *(const bf16x8*)&myP[l16 * PSTR + 32 + quad * 8];
        // row-sum on the MFMA pipe: l = P @ ones
        lacc = __builtin_amdgcn_mfma_f32_16x16x32_bf16(pa0, ones, lacc, 0, 0, 0);
        lacc = __builtin_amdgcn_mfma_f32_16x16x32_bf16(pa1, ones, lacc, 0, 0, 0);
#pragma unroll
        for (int ni = 0; ni < 4; ni++) {
            oacc[ni] = __builtin_amdgcn_mfma_f32_16x16x32_bf16(pa0, vf[ni * 2], oacc[ni], 0, 0, 0);
            oacc[ni] = __builtin_amdgcn_mfma_f32_16x16x32_bf16(pa1, vf[ni * 2 + 1], oacc[ni], 0, 0, 0);
        }
    }
    // epilogue: lacc rows align with oacc rows (q = quad*4+r) -> no cross-lane work
    float inv[4];
#pragma unroll
    for (int r = 0; r < 4; r++) inv[r] = rcp_hw(lacc[r]);
#pragma unroll
    for (int ni = 0; ni < 4; ni++) {
        int d = ni * 16 + l16;
#pragma unroll
        for (int r = 0; r < 4; r++) {
            int s = q0 + quad * 4 + r;
            ctx[(size_t)(b * S_LEN + s) * DM + h * DK + d] = f2bf(oacc[ni][r] * inv[r]);
        }
    }
}

// ---------------- RMSNorm ----------------
__global__ __launch_bounds__(256) void k_rmsnorm(const float* __restrict__ x,
                                                 const float* __restrict__ gamma,
                                                 float* __restrict__ out) {
    int row = blockIdx.x, tid = threadIdx.x;
    const floatx4* xr = (const floatx4*)(x + (size_t)row * DM);
    floatx4 v = xr[tid];
    float ss = v[0] * v[0] + v[1] * v[1] + v[2] * v[2] + v[3] * v[3];
#pragma unroll
    for (int off = 1; off < 64; off <<= 1) ss += __shfl_xor(ss, off);
    __shared__ float red[4];
    int lane = tid & 63, wid = tid >> 6;
    if (lane == 0) red[wid] = ss;
    __syncthreads();
    float tot = red[0] + red[1] + red[2] + red[3];
    float rms = rsqrtf(tot * (1.0f / DM) + 1e-6f);
    floatx4 g = ((const floatx4*)gamma)[tid];
    floatx4 o;
    o[0] = v[0] * rms * g[0];
    o[1] = v[1] * rms * g[1];
    o[2] = v[2] * rms * g[2];
    o[3] = v[3] * rms * g[3];
    ((floatx4*)(out + (size_t)row * DM))[tid] = o;
}

extern "C" void kernel_launch(void* const* d_in, const int* in_sizes, int n_in,
                              void* d_out, int out_size, void* d_ws, size_t ws_size,
                              hipStream_t stream) {
    const float* Q = (const float*)d_in[0];
    const float* K = (const float*)d_in[1];
    const float* V = (const float*)d_in[2];
    const int* mask = (const int*)d_in[3];
    const float* wq = (const float*)d_in[4];
    const float* bq = (const float*)d_in[5];
    const float* wk = (const float*)d_in[6];
    const float* bk = (const float*)d_in[7];
    const float* wv = (const float*)d_in[8];
    const float* bv = (const float*)d_in[9];
    const float* wo = (const float*)d_in[10];
    const float* bo = (const float*)d_in[11];
    const float* wnq = (const float*)d_in[12];
    const float* bnq = (const float*)d_in[13];
    const float* wnk = (const float*)d_in[14];
    const float* bnk = (const float*)d_in[15];
    const float* temp = (const float*)d_in[16];
    const float* gamma = (const float*)d_in[17];

    char* w = (char*)d_ws;
    size_t o = 0;
    auto alloc = [&](size_t bytes) {
        char* p = w + o;
        o += (bytes + 255) & ~(size_t)255;
        return p;
    };
    unsigned short* Qb = (unsigned short*)alloc((size_t)BS * DM * 2);
    unsigned short* Kb = (unsigned short*)alloc((size_t)BS * DM * 2);
    unsigned short* Vb = (unsigned short*)alloc((size_t)BS * DM * 2);
    unsigned short* Wqt = (unsigned short*)alloc((size_t)DM * DM * 2);  /* composed */
    unsigned short* Wkt = (unsigned short*)alloc((size_t)DM * DM * 2);  /* composed */
    unsigned short* Wvt = (unsigned short*)alloc((size_t)DM * DM * 2);
    unsigned short* Wot = (unsigned short*)alloc((size_t)DM * DM * 2);
    float* bqc = (float*)alloc((size_t)DM * 4);
    float* bkc = (float*)alloc((size_t)DM * 4);
    unsigned short* vfrag = (unsigned short*)alloc((size_t)BHS * DK * 2);
    unsigned short* qfb = (unsigned short*)alloc((size_t)BHS * DK * 2);
    unsigned short* kfrag = (unsigned short*)alloc((size_t)BHS * DK * 2);
    unsigned int* mb = (unsigned int*)alloc((size_t)S_LEN * (S_LEN / 32) * 4);
    unsigned short* ctx = (unsigned short*)alloc((size_t)BS * DM * 2);
    float* outt = (float*)alloc((size_t)BS * DM * 4);

    k_prep<<<dim3(NCONV + NTRB2 + NCMP + NBC + NMSK), 256, 0, stream>>>(
        Q, K, V, Qb, Kb, Vb, wq, wk, wv, wo, Wqt, Wkt, Wvt, Wot,
        wnq, wnk, bq, bk, bnq, bnk, bqc, bkc, mask, mb);

    k_gemm_qkv<<<dim3(32, 8, 3), 256, 0, stream>>>(Qb, Kb, Vb, Wqt, Wkt, Wvt,
                                                   bqc, bkc, bv, temp,
                                                   qfb, kfrag, vfrag);

    k_attn<<<dim3(BATCH * NH, S_LEN / 64), 256, 0, stream>>>(
        qfb, kfrag, vfrag, (const unsigned long long*)mb, ctx);

    k_gemm_out<<<dim3(32, 16), 256, 0, stream>>>(ctx, Wot, bo, outt);
    k_rmsnorm<<<dim3(BS), 256, 0, stream>>>(outt, gamma, (float*)d_out);
}